// Round 2
// baseline (62.444 us; speedup 1.0000x reference)
//
#include <hip/hip_runtime.h>

// DenseByItems: out[b,k] = dot(V[items[b,k]], seq[b]) + B[items[b,k]]
// seq: [4096,128] f32, items: [4096,200] i32, V: [100000,128] f32, B: [100000] f32
// out: [4096,200] f32

#define BATCH 4096
#define KITEMS 200
#define DIM 128

__device__ __forceinline__ float dot8(const float4& s0, const float4& s1,
                                      const float4& a0, const float4& a1) {
    return s0.x * a0.x + s0.y * a0.y + s0.z * a0.z + s0.w * a0.w
         + s1.x * a1.x + s1.y * a1.y + s1.z * a1.z + s1.w * a1.w;
}

__global__ __launch_bounds__(256, 4) void dense_by_items_kernel(
    const float* __restrict__ seq,    // [BATCH, DIM]
    const int*   __restrict__ items,  // [BATCH, KITEMS]
    const float* __restrict__ V,      // [NUM_ITEMS, DIM]
    const float* __restrict__ Bias,   // [NUM_ITEMS]
    float*       __restrict__ out)    // [BATCH, KITEMS]
{
    const int b    = blockIdx.x;
    const int tid  = threadIdx.x;
    const int lane = tid & 63;
    const int wave = tid >> 6;   // 0..3
    const int sub  = lane & 15;  // position within 16-lane group
    const int gid  = (wave << 2) + (lane >> 4);  // 0..15: group id within block

    __shared__ int s_items[KITEMS];
    if (tid < KITEMS) s_items[tid] = items[b * KITEMS + tid];
    __syncthreads();

    // Lane owns seq elements {sub*4..sub*4+3} and {64+sub*4..64+sub*4+3}:
    // matches V loads v4[sub], v4[sub+16] -> each load instruction covers a
    // CONTIGUOUS 256B segment of the row across the 16 lanes.
    const float4* seq4 = reinterpret_cast<const float4*>(seq + (size_t)b * DIM);
    const float4 s0 = seq4[sub];
    const float4 s1 = seq4[sub + 16];

    float* outb = out + (size_t)b * KITEMS;

    // Main: items k = gid + 16*j, j = 0..11 (covers k in [0,192)), unrolled x2.
    #pragma unroll
    for (int j = 0; j < 12; j += 2) {
        const int ka = gid + 16 * j;
        const int kb = ka + 16;
        const int item_a = s_items[ka];
        const int item_b = s_items[kb];

        const float4* va = reinterpret_cast<const float4*>(V + (size_t)item_a * DIM);
        const float4* vb = reinterpret_cast<const float4*>(V + (size_t)item_b * DIM);

        // Issue all loads up front (4 vector loads + 2 bias loads in flight).
        const float4 a0 = va[sub];
        const float4 a1 = va[sub + 16];
        const float4 b0 = vb[sub];
        const float4 b1 = vb[sub + 16];
        const float bias_a = Bias[item_a];
        const float bias_b = Bias[item_b];

        float pa = dot8(s0, s1, a0, a1);
        float pb = dot8(s0, s1, b0, b1);

        // Two independent reduce chains; interleaved -> pipelined DS ops.
        pa += __shfl_xor(pa, 1);
        pb += __shfl_xor(pb, 1);
        pa += __shfl_xor(pa, 2);
        pb += __shfl_xor(pb, 2);
        pa += __shfl_xor(pa, 4);
        pb += __shfl_xor(pb, 4);
        pa += __shfl_xor(pa, 8);
        pb += __shfl_xor(pb, 8);

        if (sub == 0) {
            outb[ka] = pa + bias_a;
            outb[kb] = pb + bias_b;
        }
    }

    // Tail: k = 192 + gid for gid < 8 (covers k in [192,200)).
    if (gid < 8) {
        const int k = 192 + gid;
        const int item = s_items[k];
        const float4* va = reinterpret_cast<const float4*>(V + (size_t)item * DIM);
        const float4 a0 = va[sub];
        const float4 a1 = va[sub + 16];
        const float bias = Bias[item];

        float p = dot8(s0, s1, a0, a1);
        p += __shfl_xor(p, 1);
        p += __shfl_xor(p, 2);
        p += __shfl_xor(p, 4);
        p += __shfl_xor(p, 8);
        if (sub == 0) {
            outb[k] = p + bias;
        }
    }
}

extern "C" void kernel_launch(void* const* d_in, const int* in_sizes, int n_in,
                              void* d_out, int out_size, void* d_ws, size_t ws_size,
                              hipStream_t stream) {
    const float* seq   = (const float*)d_in[0];
    const int*   items = (const int*)d_in[1];
    const float* V     = (const float*)d_in[2];
    const float* Bias  = (const float*)d_in[3];
    float*       out   = (float*)d_out;

    dense_by_items_kernel<<<dim3(BATCH), dim3(256), 0, stream>>>(seq, items, V, Bias, out);
}